// Round 13
// baseline (61.066 us; speedup 1.0000x reference)
//
#include <hip/hip_runtime.h>
#include <math.h>
#include <stdint.h>

#define B_    8
#define N_    2048
#define FIN   256
#define FO    128
#define ALPHA 0.2f
#define NCHUNK 32
#define CHUNK  64    // N_/NCHUNK

typedef __attribute__((ext_vector_type(8))) __bf16 bf16x8;
typedef __attribute__((ext_vector_type(8))) short short8_t;
typedef __attribute__((ext_vector_type(4))) short short4_t;
typedef __attribute__((ext_vector_type(4))) float f32x4;

// ---------------- workspace layout (float elements) ----------------
static const size_t OFF_WH    = 0;                                    // B*N*FO
static const size_t OFF_S1P   = OFF_WH    + (size_t)B_*N_*FO;         // 4*B*N (four n-group partials)
static const size_t OFF_S2P   = OFF_S1P   + (size_t)4*B_*N_;          // 4*B*N
static const size_t OFF_SSORT = OFF_S2P   + (size_t)4*B_*N_;
static const size_t OFF_SORD  = OFF_SSORT + (size_t)B_*N_;
static const size_t OFF_E2P   = OFF_SORD  + (size_t)B_*N_;
static const size_t OFF_E2N   = OFF_E2P   + (size_t)B_*N_;
static const size_t OFF_DPN   = OFF_E2N   + (size_t)B_*N_;            // float2 * B*N
static const size_t OFF_KCUT  = OFF_DPN   + (size_t)2*B_*N_;
static const size_t OFF_SPN   = OFF_KCUT  + (size_t)B_*N_;            // float2 * B*N*FO (sparse: j%4==3 only)

__device__ __forceinline__ unsigned short bf16_rne(float x) {
    unsigned u = __float_as_uint(x);
    unsigned r = (u + 0x7FFFu + ((u >> 16) & 1u)) >> 16;
    return (unsigned short)r;
}

// ---------------- K1: Wh = h @ W via split-bf16 MFMA (+ 4-group partial s1,s2) ----------------
// 256 blocks (BM=64, BN=128), 512 threads = 8 waves: wave = (mh 0..1) x (ng 0..3).
__global__ __launch_bounds__(512) void k1_gemm(const float* __restrict__ h,
                                               const float* __restrict__ W,
                                               const float* __restrict__ a,
                                               float* __restrict__ Wh,
                                               float* __restrict__ s1p,
                                               float* __restrict__ s2p) {
    __shared__ short hS_hi[64][40], hS_lo[64][40];     // [row][k], pad 40
    __shared__ short wS_hi[128][40], wS_lo[128][40];   // [col][k]

    const int tid  = threadIdx.x;
    const int lane = tid & 63, wv = tid >> 6;
    const int mh = wv & 1, ng = wv >> 1;
    const int l15 = lane & 15, l4 = lane >> 4;
    const int row0 = blockIdx.x * 64;

    const int h_r = tid >> 3, h_kq = (tid & 7) * 4;    // h: one float4 per thread
    const int w_c = tid & 127, w_kb = (tid >> 7) * 8;  // W: col-owner, 8 k-scalars

    f32x4 acc[2][2];
#pragma unroll
    for (int i = 0; i < 2; ++i)
#pragma unroll
        for (int j = 0; j < 2; ++j) acc[i][j] = (f32x4){0.f, 0.f, 0.f, 0.f};

    float4 hv = *(const float4*)&h[(size_t)(row0 + h_r) * FIN + h_kq];
    float wf[8];
#pragma unroll
    for (int s = 0; s < 8; ++s) wf[s] = W[(size_t)(w_kb + s) * FO + w_c];

    for (int k0 = 0; k0 < FIN; k0 += 32) {
        {
            float hf[4] = {hv.x, hv.y, hv.z, hv.w};
            short4_t hhi, hlo;
#pragma unroll
            for (int s = 0; s < 4; ++s) {
                unsigned short hb = bf16_rne(hf[s]);
                float hbf = __uint_as_float((unsigned)hb << 16);
                hhi[s] = (short)hb;
                hlo[s] = (short)bf16_rne(hf[s] - hbf);
            }
            *(short4_t*)&hS_hi[h_r][h_kq] = hhi;
            *(short4_t*)&hS_lo[h_r][h_kq] = hlo;

            short8_t whi, wlo;
#pragma unroll
            for (int s = 0; s < 8; ++s) {
                unsigned short wb = bf16_rne(wf[s]);
                float wbf = __uint_as_float((unsigned)wb << 16);
                whi[s] = (short)wb;
                wlo[s] = (short)bf16_rne(wf[s] - wbf);
            }
            *(short8_t*)&wS_hi[w_c][w_kb] = whi;
            *(short8_t*)&wS_lo[w_c][w_kb] = wlo;
        }
        __syncthreads();

        if (k0 + 32 < FIN) {
            hv = *(const float4*)&h[(size_t)(row0 + h_r) * FIN + k0 + 32 + h_kq];
#pragma unroll
            for (int s = 0; s < 8; ++s)
                wf[s] = W[(size_t)(k0 + 32 + w_kb + s) * FO + w_c];
        }

        bf16x8 a_hi[2], a_lo[2], b_hi[2], b_lo[2];
#pragma unroll
        for (int i = 0; i < 2; ++i) {
            int r = (mh * 2 + i) * 16 + l15;
            a_hi[i] = __builtin_bit_cast(bf16x8, *(short8_t*)&hS_hi[r][l4 * 8]);
            a_lo[i] = __builtin_bit_cast(bf16x8, *(short8_t*)&hS_lo[r][l4 * 8]);
        }
#pragma unroll
        for (int j = 0; j < 2; ++j) {
            int c = (ng * 2 + j) * 16 + l15;
            b_hi[j] = __builtin_bit_cast(bf16x8, *(short8_t*)&wS_hi[c][l4 * 8]);
            b_lo[j] = __builtin_bit_cast(bf16x8, *(short8_t*)&wS_lo[c][l4 * 8]);
        }
#pragma unroll
        for (int i = 0; i < 2; ++i)
#pragma unroll
            for (int j = 0; j < 2; ++j) {
                acc[i][j] = __builtin_amdgcn_mfma_f32_16x16x32_bf16(a_hi[i], b_hi[j], acc[i][j], 0, 0, 0);
                acc[i][j] = __builtin_amdgcn_mfma_f32_16x16x32_bf16(a_hi[i], b_lo[j], acc[i][j], 0, 0, 0);
                acc[i][j] = __builtin_amdgcn_mfma_f32_16x16x32_bf16(a_lo[i], b_hi[j], acc[i][j], 0, 0, 0);
            }
        __syncthreads();
    }

#pragma unroll
    for (int i = 0; i < 2; ++i)
#pragma unroll
        for (int j = 0; j < 2; ++j) {
            int colg = (ng * 2 + j) * 16 + l15;
#pragma unroll
            for (int reg = 0; reg < 4; ++reg) {
                int rowg = row0 + (mh * 2 + i) * 16 + l4 * 4 + reg;
                Wh[(size_t)rowg * FO + colg] = acc[i][j][reg];
            }
        }

    float a1v[2], a2v[2];
#pragma unroll
    for (int j = 0; j < 2; ++j) {
        int c = (ng * 2 + j) * 16 + l15;
        a1v[j] = a[c];
        a2v[j] = a[FO + c];
    }
#pragma unroll
    for (int i = 0; i < 2; ++i) {
        float p1[4], p2[4];
#pragma unroll
        for (int reg = 0; reg < 4; ++reg) {
            p1[reg] = acc[i][0][reg] * a1v[0] + acc[i][1][reg] * a1v[1];
            p2[reg] = acc[i][0][reg] * a2v[0] + acc[i][1][reg] * a2v[1];
        }
#pragma unroll
        for (int m = 1; m < 16; m <<= 1) {
#pragma unroll
            for (int reg = 0; reg < 4; ++reg) {
                p1[reg] += __shfl_xor(p1[reg], m);
                p2[reg] += __shfl_xor(p2[reg], m);
            }
        }
        if (l15 == 0) {
#pragma unroll
            for (int reg = 0; reg < 4; ++reg) {
                int rowg = row0 + (mh * 2 + i) * 16 + l4 * 4 + reg;
                s1p[(size_t)ng * (B_ * N_) + rowg] = p1[reg];
                s2p[(size_t)ng * (B_ * N_) + rowg] = p2[reg];
            }
        }
    }
}

// ---------------- K2a: brute-force rank + scatter + exps ----------------
__global__ __launch_bounds__(512) void k2a_rank(const float* __restrict__ s2p,
                                                float* __restrict__ ssort,
                                                int* __restrict__ sord,
                                                float* __restrict__ e2p,
                                                float* __restrict__ e2n) {
    __shared__ uint64_t keys[N_];   // 16 KB
    __shared__ int part[512];
    const int b = blockIdx.x >> 5, c = blockIdx.x & 31;
    const int tid = threadIdx.x;
    const size_t SZ = (size_t)B_ * N_;

    for (int t = tid; t < N_; t += 512) {
        size_t ix = (size_t)b * N_ + t;
        float s2v = s2p[ix] + s2p[SZ + ix] + s2p[2 * SZ + ix] + s2p[3 * SZ + ix];
        unsigned u = __float_as_uint(s2v);
        u = (u & 0x80000000u) ? ~u : (u | 0x80000000u);   // order-preserving map
        keys[t] = ((uint64_t)u << 16) | (unsigned)t;      // unique -> no ties
    }
    __syncthreads();

    const int le = tid & 63;
    const int e  = c * 64 + le;
    const int q  = tid >> 6;         // 0..7
    const uint64_t myk = keys[e];
    const uint64_t* kp = keys + q * 256;
    int cnt = 0;
#pragma unroll 8
    for (int kk = 0; kk < 256; ++kk) cnt += (int)(kp[kk] > myk);
    part[tid] = cnt;
    __syncthreads();

    if (tid < 64) {
        int rank = 0;
#pragma unroll
        for (int g = 0; g < 8; ++g) rank += part[tid + 64 * g];
        int ee = c * 64 + tid;
        size_t ix = (size_t)b * N_ + ee;
        float v = s2p[ix] + s2p[SZ + ix] + s2p[2 * SZ + ix] + s2p[3 * SZ + ix];
        ssort[b * N_ + rank] = v;
        sord[b * N_ + rank]  = ee;
        e2p[b * N_ + rank] = expf(v);
        e2n[b * N_ + rank] = expf(ALPHA * v);
    }
}

// ---------------- KX: chunk-local prefixes, grain-4 sparse stores (blocks 0..255) ∪ scan+cutoffs (256..263) ----------------
__global__ __launch_bounds__(512) void kx_scan(const float* __restrict__ Wh,
                                               const int* __restrict__ sord,
                                               const float* __restrict__ e2p,
                                               const float* __restrict__ e2n,
                                               const float* __restrict__ ssort,
                                               const float* __restrict__ s1p,
                                               float2* __restrict__ SPN,
                                               float2* __restrict__ DPN,
                                               int* __restrict__ kcut) {
    __shared__ float2 qt[4][FO];     // chunk part
    __shared__ float sv[N_];         // scan part
    __shared__ float2 wsum[8];
    const int tid = threadIdx.x;
    const int bid = blockIdx.x;
    const size_t SZ = (size_t)B_ * N_;

    if (bid < 256) {
        // one 64-chunk; q = tid>>7 owns 16 positions; stores only j%4==3 positions
        const int b = bid >> 5, ch = bid & 31;
        const int f = tid & 127, q = tid >> 7;
        const size_t base = (size_t)b * N_;
        const int ks = ch * CHUNK + q * 16;   // multiple of 4

        int ords[16]; float wp[16], wn[16], xv[16];
#pragma unroll
        for (int j = 0; j < 16; ++j) ords[j] = sord[base + ks + j];
#pragma unroll
        for (int j = 0; j < 16; ++j) { wp[j] = e2p[base + ks + j]; wn[j] = e2n[base + ks + j]; }
#pragma unroll
        for (int j = 0; j < 16; ++j) xv[j] = Wh[(base + ords[j]) * FO + f];

        float2 s[16];
        float ap = 0.f, an = 0.f;
#pragma unroll
        for (int j = 0; j < 16; ++j) {
            ap += wp[j] * xv[j];
            an += wn[j] * xv[j];
            s[j] = make_float2(ap, an);
        }
        qt[q][f] = make_float2(ap, an);
        __syncthreads();

        float op = 0.f, on = 0.f;
#pragma unroll
        for (int q2 = 0; q2 < 3; ++q2)
            if (q2 < q) { op += qt[q2][f].x; on += qt[q2][f].y; }

#pragma unroll
        for (int j = 3; j < 16; j += 4)
            SPN[(base + ks + j) * FO + f] = make_float2(s[j].x + op, s[j].y + on);
    } else {
        // per-batch scalar scan + cutoffs
        const int b = bid - 256;
        const size_t base = (size_t)b * N_;

        float v[4], pv[4], nv[4], lp[4], ln[4];
        *(float4*)&v[0]  = *(const float4*)&ssort[base + tid * 4];
        *(float4*)&pv[0] = *(const float4*)&e2p[base + tid * 4];
        *(float4*)&nv[0] = *(const float4*)&e2n[base + tid * 4];
        float ap = 0.f, an = 0.f;
#pragma unroll
        for (int j = 0; j < 4; ++j) {
            sv[tid * 4 + j] = v[j];
            ap += pv[j]; lp[j] = ap;
            an += nv[j]; ln[j] = an;
        }

        float ip = ap, in2 = an;
        const int lane = tid & 63;
#pragma unroll
        for (int off = 1; off < 64; off <<= 1) {
            float tpv = __shfl_up(ip, off);
            float tnv = __shfl_up(in2, off);
            if (lane >= off) { ip += tpv; in2 += tnv; }
        }
        if (lane == 63) wsum[tid >> 6] = make_float2(ip, in2);
        __syncthreads();

        float basP = ip - ap, basN = in2 - an;
        const int w = tid >> 6;
#pragma unroll
        for (int w2 = 0; w2 < 7; ++w2)
            if (w2 < w) { basP += wsum[w2].x; basN += wsum[w2].y; }
#pragma unroll
        for (int j = 0; j < 4; ++j)
            DPN[base + tid * 4 + j] = make_float2(lp[j] + basP, ln[j] + basN);

        float tgt[4];
        int lo[4], hi[4];
#pragma unroll
        for (int r = 0; r < 4; ++r) {
            size_t row = base + tid + 512 * r;
            tgt[r] = -(s1p[row] + s1p[SZ + row] + s1p[2 * SZ + row] + s1p[3 * SZ + row]);
            lo[r] = 0; hi[r] = N_;
        }
#pragma unroll
        for (int step = 0; step < 11; ++step) {
#pragma unroll
            for (int r = 0; r < 4; ++r) {
                int mid = (lo[r] + hi[r]) >> 1;
                bool live = lo[r] < hi[r];
                float pv2 = sv[mid & (N_ - 1)];
                bool cc = live && (pv2 >= tgt[r]);
                lo[r] = cc ? mid + 1 : lo[r];
                hi[r] = (live && !cc) ? mid : hi[r];
            }
        }
#pragma unroll
        for (int r = 0; r < 4; ++r) kcut[base + tid + 512 * r] = lo[r];
    }
}

// ---------------- K4: per-32-row block; ct scan + sparse SPN + <=3-row hoisted tail ----------------
// grid = 512 blocks, 512 threads (4 rows x 128 f per iteration, 8 iters)
__global__ __launch_bounds__(512) void k4_final(const float* __restrict__ s1p,
                                                const int* __restrict__ kcut,
                                                const float2* __restrict__ DPN,
                                                const float2* __restrict__ SPN,
                                                const float* __restrict__ Wh,
                                                const int* __restrict__ sord,
                                                const float* __restrict__ e2p,
                                                const float* __restrict__ e2n,
                                                float* __restrict__ out) {
    __shared__ float2 ct[NCHUNK][FO];        // 32 KB -> becomes exclusive prefix
    __shared__ float2 qTot[4][FO];           // 4 KB
    __shared__ float sntN_lds[FO];
    __shared__ float2 s1e_lds[32];           // (exp(s1), exp(a*s1)) per row
    __shared__ float2 dpn_lds[32];           // DPN[km1] per row
    __shared__ int    k_lds[32];

    const int bid = blockIdx.x;
    const int b   = bid >> 6;                // 64 blocks per batch
    const int r0  = (bid & 63) * 32;         // first row of this block
    const int tid = threadIdx.x;
    const int f = tid & 127, rr = tid >> 7;  // rr = 0..3
    const size_t base = (size_t)b * N_;
    const size_t SZ = (size_t)B_ * N_;

    // 1) stage 32 chunk totals (last position of each chunk: 63 % 4 == 3, stored)
    for (int idx = tid; idx < NCHUNK * FO; idx += 512) {
        int c = idx >> 7, ff = idx & 127;
        ct[c][ff] = SPN[(base + c * CHUNK + CHUNK - 1) * FO + ff];
    }
    // stage per-row scalars
    if (tid < 32) {
        int row = r0 + tid;
        int k = kcut[base + row];
        k_lds[tid] = k;
        size_t rix = base + row;
        float s1v = s1p[rix] + s1p[SZ + rix] + s1p[2 * SZ + rix] + s1p[3 * SZ + rix];
        s1e_lds[tid] = make_float2(expf(s1v), expf(ALPHA * s1v));
        dpn_lds[tid] = (k > 0) ? DPN[base + k - 1] : make_float2(0.f, 0.f);
    }
    __syncthreads();

    // 2) exclusive scan over 32 chunks: 4 quarters of 8 + fixup
    float rp = 0.f, rn = 0.f;
    for (int c = rr * 8; c < rr * 8 + 8; ++c) {
        float2 t = ct[c][f];
        ct[c][f] = make_float2(rp, rn);
        rp += t.x; rn += t.y;
    }
    qTot[rr][f] = make_float2(rp, rn);
    __syncthreads();
    float addP = 0.f, addN = 0.f;
#pragma unroll
    for (int q2 = 0; q2 < 3; ++q2)
        if (q2 < rr) { addP += qTot[q2][f].x; addN += qTot[q2][f].y; }
    if (rr > 0) {
        for (int c = rr * 8; c < rr * 8 + 8; ++c) {
            float2 t = ct[c][f];
            ct[c][f] = make_float2(t.x + addP, t.y + addN);
        }
    }
    if (tid < FO)
        sntN_lds[tid] = qTot[0][tid].y + qTot[1][tid].y + qTot[2][tid].y + qTot[3][tid].y;
    __syncthreads();

    const float dnt = DPN[base + N_ - 1].y;
    const float sntN = sntN_lds[f];

    // 3) hoist all loads for all 8 row-iterations, then combine + store.
    // km1 decomposition: rem = (km1+1)&3; pbase = km1-rem (≡3 mod 4, stored);
    // sp = ct[c32] + (pbase in same chunk ? SPN[pbase] : 0) + Σ_{j=pbase+1..km1} w_j·Wh[ord_j]
    float2 sl[8], ov[8];
    float tx[8][3], twp[8][3], twn[8][3];
    int kv[8];
#pragma unroll
    for (int it = 0; it < 8; ++it) {
        const int lr = it * 4 + rr;
        const int k = k_lds[lr];
        kv[it] = k;
        const int km1 = (k > 0) ? (k - 1) : 0;
        const int c32 = km1 >> 6;
        const int rem = (k > 0) ? ((km1 + 1) & 3) : 0;
        const int pbase = km1 - rem;
        const bool useSPN = (k > 0) && (rem == 0 || (pbase >= 0 && (pbase >> 6) == c32));
        const int spnIdx = (rem == 0) ? km1 : (useSPN ? pbase : km1);
        sl[it] = useSPN ? SPN[(base + spnIdx) * FO + f] : make_float2(0.f, 0.f);
        ov[it] = (k > 0) ? ct[c32][f] : make_float2(0.f, 0.f);
#pragma unroll
        for (int t = 0; t < 3; ++t) {
            const bool act = (k > 0) && (t < rem);
            int j = pbase + 1 + t;
            j = act ? j : km1;                 // clamp to a safe index
            const int ord = sord[base + j];    // wave-uniform
            twp[it][t] = act ? e2p[base + j] : 0.f;
            twn[it][t] = act ? e2n[base + j] : 0.f;
            tx[it][t]  = Wh[(base + ord) * FO + f];
        }
    }
#pragma unroll
    for (int it = 0; it < 8; ++it) {
        const int lr  = it * 4 + rr;
        const int row = r0 + lr;
        const float2 e1 = s1e_lds[lr];
        const float2 d  = dpn_lds[lr];

        float sp = 0.f, sn = 0.f;
        if (kv[it] > 0) {
            sp = ov[it].x + sl[it].x;
            sn = ov[it].y + sl[it].y;
#pragma unroll
            for (int t = 0; t < 3; ++t) {
                sp += twp[it][t] * tx[it][t];
                sn += twn[it][t] * tx[it][t];
            }
        }
        const float den = e1.x * d.x + e1.y * (dnt - d.y);
        const float num = e1.x * sp + e1.y * (sntN - sn);
        const float o = num / den;
        out[((size_t)b * N_ + row) * FO + f] = (o > 0.f) ? o : (expf(o) - 1.f);
    }
}

// ---------------- launch ----------------
extern "C" void kernel_launch(void* const* d_in, const int* in_sizes, int n_in,
                              void* d_out, int out_size, void* d_ws, size_t ws_size,
                              hipStream_t stream) {
    const float* h = (const float*)d_in[0];
    const float* W = (const float*)d_in[1];
    const float* a = (const float*)d_in[2];
    float* out = (float*)d_out;
    float* ws = (float*)d_ws;

    float*  Wh    = ws + OFF_WH;
    float*  s1p   = ws + OFF_S1P;
    float*  s2p   = ws + OFF_S2P;
    float*  ssort = ws + OFF_SSORT;
    int*    sord  = (int*)(ws + OFF_SORD);
    float*  e2p   = ws + OFF_E2P;
    float*  e2n   = ws + OFF_E2N;
    float2* DPN   = (float2*)(ws + OFF_DPN);
    int*    kcut  = (int*)(ws + OFF_KCUT);
    float2* SPN   = (float2*)(ws + OFF_SPN);

    k1_gemm<<<dim3(B_ * N_ / 64), dim3(512), 0, stream>>>(h, W, a, Wh, s1p, s2p);
    k2a_rank<<<dim3(B_ * 32), dim3(512), 0, stream>>>(s2p, ssort, sord, e2p, e2n);
    kx_scan<<<dim3(264), dim3(512), 0, stream>>>(Wh, sord, e2p, e2n, ssort, s1p,
                                                 SPN, DPN, kcut);
    k4_final<<<dim3(512), dim3(512), 0, stream>>>(s1p, kcut, DPN, SPN,
                                                  Wh, sord, e2p, e2n, out);
}

// Round 14
// 45.268 us; speedup vs baseline: 1.3490x; 1.3490x over previous
//
#include <hip/hip_runtime.h>
#include <math.h>
#include <stdint.h>

#define B_    8
#define N_    2048
#define FIN   256
#define FO    128
#define ALPHA 0.2f
#define NCHUNK 32
#define CHUNK  64    // N_/NCHUNK

typedef __attribute__((ext_vector_type(8))) __bf16 bf16x8;
typedef __attribute__((ext_vector_type(8))) short short8_t;
typedef __attribute__((ext_vector_type(4))) short short4_t;
typedef __attribute__((ext_vector_type(4))) float f32x4;

// ---------------- workspace layout (float elements) ----------------
static const size_t OFF_WH    = 0;                                    // B*N*FO
static const size_t OFF_S1P   = OFF_WH    + (size_t)B_*N_*FO;         // 4*B*N (four n-group partials)
static const size_t OFF_S2P   = OFF_S1P   + (size_t)4*B_*N_;          // 4*B*N
static const size_t OFF_SSORT = OFF_S2P   + (size_t)4*B_*N_;
static const size_t OFF_SORD  = OFF_SSORT + (size_t)B_*N_;
static const size_t OFF_E2P   = OFF_SORD  + (size_t)B_*N_;
static const size_t OFF_E2N   = OFF_E2P   + (size_t)B_*N_;
static const size_t OFF_DPN   = OFF_E2N   + (size_t)B_*N_;            // float2 * B*N
static const size_t OFF_KCUT  = OFF_DPN   + (size_t)2*B_*N_;
static const size_t OFF_SPN   = OFF_KCUT  + (size_t)B_*N_;            // float2 * B*N*FO (chunk-local prefixes)

__device__ __forceinline__ unsigned short bf16_rne(float x) {
    unsigned u = __float_as_uint(x);
    unsigned r = (u + 0x7FFFu + ((u >> 16) & 1u)) >> 16;
    return (unsigned short)r;
}

// ---------------- K1: Wh = h @ W via split-bf16 MFMA (+ 4-group partial s1,s2) ----------------
// 256 blocks (BM=64, BN=128), 512 threads = 8 waves: wave = (mh 0..1) x (ng 0..3).
__global__ __launch_bounds__(512) void k1_gemm(const float* __restrict__ h,
                                               const float* __restrict__ W,
                                               const float* __restrict__ a,
                                               float* __restrict__ Wh,
                                               float* __restrict__ s1p,
                                               float* __restrict__ s2p) {
    __shared__ short hS_hi[64][40], hS_lo[64][40];     // [row][k], pad 40
    __shared__ short wS_hi[128][40], wS_lo[128][40];   // [col][k]

    const int tid  = threadIdx.x;
    const int lane = tid & 63, wv = tid >> 6;
    const int mh = wv & 1, ng = wv >> 1;
    const int l15 = lane & 15, l4 = lane >> 4;
    const int row0 = blockIdx.x * 64;

    const int h_r = tid >> 3, h_kq = (tid & 7) * 4;    // h: one float4 per thread
    const int w_c = tid & 127, w_kb = (tid >> 7) * 8;  // W: col-owner, 8 k-scalars

    f32x4 acc[2][2];
#pragma unroll
    for (int i = 0; i < 2; ++i)
#pragma unroll
        for (int j = 0; j < 2; ++j) acc[i][j] = (f32x4){0.f, 0.f, 0.f, 0.f};

    float4 hv = *(const float4*)&h[(size_t)(row0 + h_r) * FIN + h_kq];
    float wf[8];
#pragma unroll
    for (int s = 0; s < 8; ++s) wf[s] = W[(size_t)(w_kb + s) * FO + w_c];

    for (int k0 = 0; k0 < FIN; k0 += 32) {
        {
            float hf[4] = {hv.x, hv.y, hv.z, hv.w};
            short4_t hhi, hlo;
#pragma unroll
            for (int s = 0; s < 4; ++s) {
                unsigned short hb = bf16_rne(hf[s]);
                float hbf = __uint_as_float((unsigned)hb << 16);
                hhi[s] = (short)hb;
                hlo[s] = (short)bf16_rne(hf[s] - hbf);
            }
            *(short4_t*)&hS_hi[h_r][h_kq] = hhi;
            *(short4_t*)&hS_lo[h_r][h_kq] = hlo;

            short8_t whi, wlo;
#pragma unroll
            for (int s = 0; s < 8; ++s) {
                unsigned short wb = bf16_rne(wf[s]);
                float wbf = __uint_as_float((unsigned)wb << 16);
                whi[s] = (short)wb;
                wlo[s] = (short)bf16_rne(wf[s] - wbf);
            }
            *(short8_t*)&wS_hi[w_c][w_kb] = whi;
            *(short8_t*)&wS_lo[w_c][w_kb] = wlo;
        }
        __syncthreads();

        if (k0 + 32 < FIN) {
            hv = *(const float4*)&h[(size_t)(row0 + h_r) * FIN + k0 + 32 + h_kq];
#pragma unroll
            for (int s = 0; s < 8; ++s)
                wf[s] = W[(size_t)(k0 + 32 + w_kb + s) * FO + w_c];
        }

        bf16x8 a_hi[2], a_lo[2], b_hi[2], b_lo[2];
#pragma unroll
        for (int i = 0; i < 2; ++i) {
            int r = (mh * 2 + i) * 16 + l15;
            a_hi[i] = __builtin_bit_cast(bf16x8, *(short8_t*)&hS_hi[r][l4 * 8]);
            a_lo[i] = __builtin_bit_cast(bf16x8, *(short8_t*)&hS_lo[r][l4 * 8]);
        }
#pragma unroll
        for (int j = 0; j < 2; ++j) {
            int c = (ng * 2 + j) * 16 + l15;
            b_hi[j] = __builtin_bit_cast(bf16x8, *(short8_t*)&wS_hi[c][l4 * 8]);
            b_lo[j] = __builtin_bit_cast(bf16x8, *(short8_t*)&wS_lo[c][l4 * 8]);
        }
#pragma unroll
        for (int i = 0; i < 2; ++i)
#pragma unroll
            for (int j = 0; j < 2; ++j) {
                acc[i][j] = __builtin_amdgcn_mfma_f32_16x16x32_bf16(a_hi[i], b_hi[j], acc[i][j], 0, 0, 0);
                acc[i][j] = __builtin_amdgcn_mfma_f32_16x16x32_bf16(a_hi[i], b_lo[j], acc[i][j], 0, 0, 0);
                acc[i][j] = __builtin_amdgcn_mfma_f32_16x16x32_bf16(a_lo[i], b_hi[j], acc[i][j], 0, 0, 0);
            }
        __syncthreads();
    }

#pragma unroll
    for (int i = 0; i < 2; ++i)
#pragma unroll
        for (int j = 0; j < 2; ++j) {
            int colg = (ng * 2 + j) * 16 + l15;
#pragma unroll
            for (int reg = 0; reg < 4; ++reg) {
                int rowg = row0 + (mh * 2 + i) * 16 + l4 * 4 + reg;
                Wh[(size_t)rowg * FO + colg] = acc[i][j][reg];
            }
        }

    float a1v[2], a2v[2];
#pragma unroll
    for (int j = 0; j < 2; ++j) {
        int c = (ng * 2 + j) * 16 + l15;
        a1v[j] = a[c];
        a2v[j] = a[FO + c];
    }
#pragma unroll
    for (int i = 0; i < 2; ++i) {
        float p1[4], p2[4];
#pragma unroll
        for (int reg = 0; reg < 4; ++reg) {
            p1[reg] = acc[i][0][reg] * a1v[0] + acc[i][1][reg] * a1v[1];
            p2[reg] = acc[i][0][reg] * a2v[0] + acc[i][1][reg] * a2v[1];
        }
#pragma unroll
        for (int m = 1; m < 16; m <<= 1) {
#pragma unroll
            for (int reg = 0; reg < 4; ++reg) {
                p1[reg] += __shfl_xor(p1[reg], m);
                p2[reg] += __shfl_xor(p2[reg], m);
            }
        }
        if (l15 == 0) {
#pragma unroll
            for (int reg = 0; reg < 4; ++reg) {
                int rowg = row0 + (mh * 2 + i) * 16 + l4 * 4 + reg;
                s1p[(size_t)ng * (B_ * N_) + rowg] = p1[reg];
                s2p[(size_t)ng * (B_ * N_) + rowg] = p2[reg];
            }
        }
    }
}

// ---------------- K2a: brute-force rank + scatter + exps ----------------
__global__ __launch_bounds__(512) void k2a_rank(const float* __restrict__ s2p,
                                                float* __restrict__ ssort,
                                                int* __restrict__ sord,
                                                float* __restrict__ e2p,
                                                float* __restrict__ e2n) {
    __shared__ uint64_t keys[N_];   // 16 KB
    __shared__ int part[512];
    const int b = blockIdx.x >> 5, c = blockIdx.x & 31;
    const int tid = threadIdx.x;
    const size_t SZ = (size_t)B_ * N_;

    for (int t = tid; t < N_; t += 512) {
        size_t ix = (size_t)b * N_ + t;
        float s2v = s2p[ix] + s2p[SZ + ix] + s2p[2 * SZ + ix] + s2p[3 * SZ + ix];
        unsigned u = __float_as_uint(s2v);
        u = (u & 0x80000000u) ? ~u : (u | 0x80000000u);   // order-preserving map
        keys[t] = ((uint64_t)u << 16) | (unsigned)t;      // unique -> no ties
    }
    __syncthreads();

    const int le = tid & 63;
    const int e  = c * 64 + le;
    const int q  = tid >> 6;         // 0..7
    const uint64_t myk = keys[e];
    const uint64_t* kp = keys + q * 256;
    int cnt = 0;
#pragma unroll 8
    for (int kk = 0; kk < 256; ++kk) cnt += (int)(kp[kk] > myk);
    part[tid] = cnt;
    __syncthreads();

    if (tid < 64) {
        int rank = 0;
#pragma unroll
        for (int g = 0; g < 8; ++g) rank += part[tid + 64 * g];
        int ee = c * 64 + tid;
        size_t ix = (size_t)b * N_ + ee;
        float v = s2p[ix] + s2p[SZ + ix] + s2p[2 * SZ + ix] + s2p[3 * SZ + ix];
        ssort[b * N_ + rank] = v;
        sord[b * N_ + rank]  = ee;
        e2p[b * N_ + rank] = expf(v);
        e2n[b * N_ + rank] = expf(ALPHA * v);
    }
}

// ---------------- KX: chunk-local full prefixes (blocks 0..255) ∪ scalar scan+cutoffs (256..263) ----------------
__global__ __launch_bounds__(512) void kx_scan(const float* __restrict__ Wh,
                                               const int* __restrict__ sord,
                                               const float* __restrict__ e2p,
                                               const float* __restrict__ e2n,
                                               const float* __restrict__ ssort,
                                               const float* __restrict__ s1p,
                                               float2* __restrict__ SPN,
                                               float2* __restrict__ DPN,
                                               int* __restrict__ kcut) {
    __shared__ float2 qt[4][FO];     // chunk part
    __shared__ float sv[N_];         // scan part
    __shared__ float2 wsum[8];
    const int tid = threadIdx.x;
    const int bid = blockIdx.x;
    const size_t SZ = (size_t)B_ * N_;

    if (bid < 256) {
        // one 64-chunk; q = tid>>7 owns 16 positions; full chunk-local prefixes out
        const int b = bid >> 5, ch = bid & 31;
        const int f = tid & 127, q = tid >> 7;
        const size_t base = (size_t)b * N_;
        const int ks = ch * CHUNK + q * 16;

        int ords[16]; float wp[16], wn[16], xv[16];
#pragma unroll
        for (int j = 0; j < 16; ++j) ords[j] = sord[base + ks + j];
#pragma unroll
        for (int j = 0; j < 16; ++j) { wp[j] = e2p[base + ks + j]; wn[j] = e2n[base + ks + j]; }
#pragma unroll
        for (int j = 0; j < 16; ++j) xv[j] = Wh[(base + ords[j]) * FO + f];

        float2 s[16];
        float ap = 0.f, an = 0.f;
#pragma unroll
        for (int j = 0; j < 16; ++j) {
            ap += wp[j] * xv[j];
            an += wn[j] * xv[j];
            s[j] = make_float2(ap, an);
        }
        qt[q][f] = make_float2(ap, an);
        __syncthreads();

        float op = 0.f, on = 0.f;
#pragma unroll
        for (int q2 = 0; q2 < 3; ++q2)
            if (q2 < q) { op += qt[q2][f].x; on += qt[q2][f].y; }

#pragma unroll
        for (int j = 0; j < 16; ++j)
            SPN[(base + ks + j) * FO + f] = make_float2(s[j].x + op, s[j].y + on);
    } else {
        // per-batch scalar scan + cutoffs
        const int b = bid - 256;
        const size_t base = (size_t)b * N_;

        float v[4], pv[4], nv[4], lp[4], ln[4];
        *(float4*)&v[0]  = *(const float4*)&ssort[base + tid * 4];
        *(float4*)&pv[0] = *(const float4*)&e2p[base + tid * 4];
        *(float4*)&nv[0] = *(const float4*)&e2n[base + tid * 4];
        float ap = 0.f, an = 0.f;
#pragma unroll
        for (int j = 0; j < 4; ++j) {
            sv[tid * 4 + j] = v[j];
            ap += pv[j]; lp[j] = ap;
            an += nv[j]; ln[j] = an;
        }

        float ip = ap, in2 = an;
        const int lane = tid & 63;
#pragma unroll
        for (int off = 1; off < 64; off <<= 1) {
            float tpv = __shfl_up(ip, off);
            float tnv = __shfl_up(in2, off);
            if (lane >= off) { ip += tpv; in2 += tnv; }
        }
        if (lane == 63) wsum[tid >> 6] = make_float2(ip, in2);
        __syncthreads();

        float basP = ip - ap, basN = in2 - an;
        const int w = tid >> 6;
#pragma unroll
        for (int w2 = 0; w2 < 7; ++w2)
            if (w2 < w) { basP += wsum[w2].x; basN += wsum[w2].y; }
#pragma unroll
        for (int j = 0; j < 4; ++j)
            DPN[base + tid * 4 + j] = make_float2(lp[j] + basP, ln[j] + basN);

        float tgt[4];
        int lo[4], hi[4];
#pragma unroll
        for (int r = 0; r < 4; ++r) {
            size_t row = base + tid + 512 * r;
            tgt[r] = -(s1p[row] + s1p[SZ + row] + s1p[2 * SZ + row] + s1p[3 * SZ + row]);
            lo[r] = 0; hi[r] = N_;
        }
#pragma unroll
        for (int step = 0; step < 11; ++step) {
#pragma unroll
            for (int r = 0; r < 4; ++r) {
                int mid = (lo[r] + hi[r]) >> 1;
                bool live = lo[r] < hi[r];
                float pv2 = sv[mid & (N_ - 1)];
                bool cc = live && (pv2 >= tgt[r]);
                lo[r] = cc ? mid + 1 : lo[r];
                hi[r] = (live && !cc) ? mid : hi[r];
            }
        }
#pragma unroll
        for (int r = 0; r < 4; ++r) kcut[base + tid + 512 * r] = lo[r];
    }
}

// ---------------- K4: per-32-row block; ct scan + 1 prefix load per row; no gather ----------------
// grid = 512 blocks, 512 threads (4 rows x 128 f per iteration, 8 iters)
__global__ __launch_bounds__(512) void k4_final(const float* __restrict__ s1p,
                                                const int* __restrict__ kcut,
                                                const float2* __restrict__ DPN,
                                                const float2* __restrict__ SPN,
                                                float* __restrict__ out) {
    __shared__ float2 ct[NCHUNK][FO];        // 32 KB -> becomes exclusive prefix
    __shared__ float2 qTot[4][FO];           // 4 KB
    __shared__ float sntN_lds[FO];
    __shared__ float2 s1e_lds[32];           // (exp(s1), exp(a*s1)) per row
    __shared__ float2 dpn_lds[32];           // DPN[km1] per row
    __shared__ int    k_lds[32];

    const int bid = blockIdx.x;
    const int b   = bid >> 6;                // 64 blocks per batch
    const int r0  = (bid & 63) * 32;         // first row of this block
    const int tid = threadIdx.x;
    const int f = tid & 127, rr = tid >> 7;  // rr = 0..3
    const size_t base = (size_t)b * N_;
    const size_t SZ = (size_t)B_ * N_;

    // 1) stage 32 chunk totals (last position of each chunk)
    for (int idx = tid; idx < NCHUNK * FO; idx += 512) {
        int c = idx >> 7, ff = idx & 127;
        ct[c][ff] = SPN[(base + c * CHUNK + CHUNK - 1) * FO + ff];
    }
    // stage per-row scalars
    if (tid < 32) {
        int row = r0 + tid;
        int k = kcut[base + row];
        k_lds[tid] = k;
        size_t rix = base + row;
        float s1v = s1p[rix] + s1p[SZ + rix] + s1p[2 * SZ + rix] + s1p[3 * SZ + rix];
        s1e_lds[tid] = make_float2(expf(s1v), expf(ALPHA * s1v));
        dpn_lds[tid] = (k > 0) ? DPN[base + k - 1] : make_float2(0.f, 0.f);
    }
    __syncthreads();

    // 2) exclusive scan over chunks: 4 quarters of 8 + fixup
    float rp = 0.f, rn = 0.f;
    for (int c = rr * 8; c < rr * 8 + 8; ++c) {
        float2 t = ct[c][f];
        ct[c][f] = make_float2(rp, rn);
        rp += t.x; rn += t.y;
    }
    qTot[rr][f] = make_float2(rp, rn);
    __syncthreads();
    float addP = 0.f, addN = 0.f;
#pragma unroll
    for (int q2 = 0; q2 < 3; ++q2)
        if (q2 < rr) { addP += qTot[q2][f].x; addN += qTot[q2][f].y; }
    if (rr > 0) {
        for (int c = rr * 8; c < rr * 8 + 8; ++c) {
            float2 t = ct[c][f];
            ct[c][f] = make_float2(t.x + addP, t.y + addN);
        }
    }
    if (tid < FO)
        sntN_lds[tid] = qTot[0][tid].y + qTot[1][tid].y + qTot[2][tid].y + qTot[3][tid].y;
    __syncthreads();

    const float dnt = DPN[base + N_ - 1].y;
    const float sntN = sntN_lds[f];

    // 3) 8 iterations x 4 rows; one coalesced prefix load per row
#pragma unroll 2
    for (int it = 0; it < 8; ++it) {
        const int lr   = it * 4 + rr;        // local row 0..31
        const int row  = r0 + lr;
        const float2 e1 = s1e_lds[lr];
        const float2 d  = dpn_lds[lr];
        const int k = k_lds[lr];

        float sp = 0.f, sn = 0.f;
        if (k > 0) {
            const int km1 = k - 1;
            const int c32 = km1 >> 6;          // CHUNK=64
            float2 o  = ct[c32][f];
            float2 sl = SPN[(base + km1) * FO + f];
            sp = o.x + sl.x;
            sn = o.y + sl.y;
        }
        const float den = e1.x * d.x + e1.y * (dnt - d.y);
        const float num = e1.x * sp + e1.y * (sntN - sn);
        const float o = num / den;
        out[((size_t)b * N_ + row) * FO + f] = (o > 0.f) ? o : (expf(o) - 1.f);
    }
}

// ---------------- launch ----------------
extern "C" void kernel_launch(void* const* d_in, const int* in_sizes, int n_in,
                              void* d_out, int out_size, void* d_ws, size_t ws_size,
                              hipStream_t stream) {
    const float* h = (const float*)d_in[0];
    const float* W = (const float*)d_in[1];
    const float* a = (const float*)d_in[2];
    float* out = (float*)d_out;
    float* ws = (float*)d_ws;

    float*  Wh    = ws + OFF_WH;
    float*  s1p   = ws + OFF_S1P;
    float*  s2p   = ws + OFF_S2P;
    float*  ssort = ws + OFF_SSORT;
    int*    sord  = (int*)(ws + OFF_SORD);
    float*  e2p   = ws + OFF_E2P;
    float*  e2n   = ws + OFF_E2N;
    float2* DPN   = (float2*)(ws + OFF_DPN);
    int*    kcut  = (int*)(ws + OFF_KCUT);
    float2* SPN   = (float2*)(ws + OFF_SPN);

    k1_gemm<<<dim3(B_ * N_ / 64), dim3(512), 0, stream>>>(h, W, a, Wh, s1p, s2p);
    k2a_rank<<<dim3(B_ * 32), dim3(512), 0, stream>>>(s2p, ssort, sord, e2p, e2n);
    kx_scan<<<dim3(264), dim3(512), 0, stream>>>(Wh, sord, e2p, e2n, ssort, s1p,
                                                 SPN, DPN, kcut);
    k4_final<<<dim3(512), dim3(512), 0, stream>>>(s1p, kcut, DPN, SPN, out);
}

// Round 15
// 43.940 us; speedup vs baseline: 1.3897x; 1.0302x over previous
//
#include <hip/hip_runtime.h>
#include <math.h>
#include <stdint.h>

#define B_    8
#define N_    2048
#define FIN   256
#define FO    128
#define ALPHA 0.2f
#define NCHUNK 32
#define CHUNK  64    // N_/NCHUNK

typedef __attribute__((ext_vector_type(8))) __bf16 bf16x8;
typedef __attribute__((ext_vector_type(8))) short short8_t;
typedef __attribute__((ext_vector_type(4))) short short4_t;
typedef __attribute__((ext_vector_type(4))) float f32x4;

// ---------------- workspace layout (float elements) ----------------
static const size_t OFF_WH    = 0;                                    // B*N*FO
static const size_t OFF_S1P   = OFF_WH    + (size_t)B_*N_*FO;         // 4*B*N (four n-group partials)
static const size_t OFF_S2P   = OFF_S1P   + (size_t)4*B_*N_;          // 4*B*N
static const size_t OFF_SSORT = OFF_S2P   + (size_t)4*B_*N_;
static const size_t OFF_SORD  = OFF_SSORT + (size_t)B_*N_;
static const size_t OFF_E2P   = OFF_SORD  + (size_t)B_*N_;
static const size_t OFF_E2N   = OFF_E2P   + (size_t)B_*N_;
static const size_t OFF_DPN   = OFF_E2N   + (size_t)B_*N_;            // float2 * B*N
static const size_t OFF_KCUT  = OFF_DPN   + (size_t)2*B_*N_;
static const size_t OFF_SPN   = OFF_KCUT  + (size_t)B_*N_;            // u32 * B*N*FO (packed 2xbf16 prefixes)

__device__ __forceinline__ unsigned short bf16_rne(float x) {
    unsigned u = __float_as_uint(x);
    unsigned r = (u + 0x7FFFu + ((u >> 16) & 1u)) >> 16;
    return (unsigned short)r;
}
__device__ __forceinline__ unsigned pack_pn(float p, float n) {
    return ((unsigned)bf16_rne(p) << 16) | (unsigned)bf16_rne(n);
}
__device__ __forceinline__ float2 unpack_pn(unsigned v) {
    return make_float2(__uint_as_float(v & 0xFFFF0000u), __uint_as_float(v << 16));
}

// ---------------- K1: Wh = h @ W via split-bf16 MFMA (+ 4-group partial s1,s2) ----------------
// 256 blocks (BM=64, BN=128), 512 threads = 8 waves: wave = (mh 0..1) x (ng 0..3).
__global__ __launch_bounds__(512) void k1_gemm(const float* __restrict__ h,
                                               const float* __restrict__ W,
                                               const float* __restrict__ a,
                                               float* __restrict__ Wh,
                                               float* __restrict__ s1p,
                                               float* __restrict__ s2p) {
    __shared__ short hS_hi[64][40], hS_lo[64][40];     // [row][k], pad 40
    __shared__ short wS_hi[128][40], wS_lo[128][40];   // [col][k]

    const int tid  = threadIdx.x;
    const int lane = tid & 63, wv = tid >> 6;
    const int mh = wv & 1, ng = wv >> 1;
    const int l15 = lane & 15, l4 = lane >> 4;
    const int row0 = blockIdx.x * 64;

    const int h_r = tid >> 3, h_kq = (tid & 7) * 4;    // h: one float4 per thread
    const int w_c = tid & 127, w_kb = (tid >> 7) * 8;  // W: col-owner, 8 k-scalars

    f32x4 acc[2][2];
#pragma unroll
    for (int i = 0; i < 2; ++i)
#pragma unroll
        for (int j = 0; j < 2; ++j) acc[i][j] = (f32x4){0.f, 0.f, 0.f, 0.f};

    float4 hv = *(const float4*)&h[(size_t)(row0 + h_r) * FIN + h_kq];
    float wf[8];
#pragma unroll
    for (int s = 0; s < 8; ++s) wf[s] = W[(size_t)(w_kb + s) * FO + w_c];

    for (int k0 = 0; k0 < FIN; k0 += 32) {
        {
            float hf[4] = {hv.x, hv.y, hv.z, hv.w};
            short4_t hhi, hlo;
#pragma unroll
            for (int s = 0; s < 4; ++s) {
                unsigned short hb = bf16_rne(hf[s]);
                float hbf = __uint_as_float((unsigned)hb << 16);
                hhi[s] = (short)hb;
                hlo[s] = (short)bf16_rne(hf[s] - hbf);
            }
            *(short4_t*)&hS_hi[h_r][h_kq] = hhi;
            *(short4_t*)&hS_lo[h_r][h_kq] = hlo;

            short8_t whi, wlo;
#pragma unroll
            for (int s = 0; s < 8; ++s) {
                unsigned short wb = bf16_rne(wf[s]);
                float wbf = __uint_as_float((unsigned)wb << 16);
                whi[s] = (short)wb;
                wlo[s] = (short)bf16_rne(wf[s] - wbf);
            }
            *(short8_t*)&wS_hi[w_c][w_kb] = whi;
            *(short8_t*)&wS_lo[w_c][w_kb] = wlo;
        }
        __syncthreads();

        if (k0 + 32 < FIN) {
            hv = *(const float4*)&h[(size_t)(row0 + h_r) * FIN + k0 + 32 + h_kq];
#pragma unroll
            for (int s = 0; s < 8; ++s)
                wf[s] = W[(size_t)(k0 + 32 + w_kb + s) * FO + w_c];
        }

        bf16x8 a_hi[2], a_lo[2], b_hi[2], b_lo[2];
#pragma unroll
        for (int i = 0; i < 2; ++i) {
            int r = (mh * 2 + i) * 16 + l15;
            a_hi[i] = __builtin_bit_cast(bf16x8, *(short8_t*)&hS_hi[r][l4 * 8]);
            a_lo[i] = __builtin_bit_cast(bf16x8, *(short8_t*)&hS_lo[r][l4 * 8]);
        }
#pragma unroll
        for (int j = 0; j < 2; ++j) {
            int c = (ng * 2 + j) * 16 + l15;
            b_hi[j] = __builtin_bit_cast(bf16x8, *(short8_t*)&wS_hi[c][l4 * 8]);
            b_lo[j] = __builtin_bit_cast(bf16x8, *(short8_t*)&wS_lo[c][l4 * 8]);
        }
#pragma unroll
        for (int i = 0; i < 2; ++i)
#pragma unroll
            for (int j = 0; j < 2; ++j) {
                acc[i][j] = __builtin_amdgcn_mfma_f32_16x16x32_bf16(a_hi[i], b_hi[j], acc[i][j], 0, 0, 0);
                acc[i][j] = __builtin_amdgcn_mfma_f32_16x16x32_bf16(a_hi[i], b_lo[j], acc[i][j], 0, 0, 0);
                acc[i][j] = __builtin_amdgcn_mfma_f32_16x16x32_bf16(a_lo[i], b_hi[j], acc[i][j], 0, 0, 0);
            }
        __syncthreads();
    }

#pragma unroll
    for (int i = 0; i < 2; ++i)
#pragma unroll
        for (int j = 0; j < 2; ++j) {
            int colg = (ng * 2 + j) * 16 + l15;
#pragma unroll
            for (int reg = 0; reg < 4; ++reg) {
                int rowg = row0 + (mh * 2 + i) * 16 + l4 * 4 + reg;
                Wh[(size_t)rowg * FO + colg] = acc[i][j][reg];
            }
        }

    float a1v[2], a2v[2];
#pragma unroll
    for (int j = 0; j < 2; ++j) {
        int c = (ng * 2 + j) * 16 + l15;
        a1v[j] = a[c];
        a2v[j] = a[FO + c];
    }
#pragma unroll
    for (int i = 0; i < 2; ++i) {
        float p1[4], p2[4];
#pragma unroll
        for (int reg = 0; reg < 4; ++reg) {
            p1[reg] = acc[i][0][reg] * a1v[0] + acc[i][1][reg] * a1v[1];
            p2[reg] = acc[i][0][reg] * a2v[0] + acc[i][1][reg] * a2v[1];
        }
#pragma unroll
        for (int m = 1; m < 16; m <<= 1) {
#pragma unroll
            for (int reg = 0; reg < 4; ++reg) {
                p1[reg] += __shfl_xor(p1[reg], m);
                p2[reg] += __shfl_xor(p2[reg], m);
            }
        }
        if (l15 == 0) {
#pragma unroll
            for (int reg = 0; reg < 4; ++reg) {
                int rowg = row0 + (mh * 2 + i) * 16 + l4 * 4 + reg;
                s1p[(size_t)ng * (B_ * N_) + rowg] = p1[reg];
                s2p[(size_t)ng * (B_ * N_) + rowg] = p2[reg];
            }
        }
    }
}

// ---------------- K2a: brute-force rank + scatter + exps ----------------
__global__ __launch_bounds__(512) void k2a_rank(const float* __restrict__ s2p,
                                                float* __restrict__ ssort,
                                                int* __restrict__ sord,
                                                float* __restrict__ e2p,
                                                float* __restrict__ e2n) {
    __shared__ uint64_t keys[N_];   // 16 KB
    __shared__ int part[512];
    const int b = blockIdx.x >> 5, c = blockIdx.x & 31;
    const int tid = threadIdx.x;
    const size_t SZ = (size_t)B_ * N_;

    for (int t = tid; t < N_; t += 512) {
        size_t ix = (size_t)b * N_ + t;
        float s2v = s2p[ix] + s2p[SZ + ix] + s2p[2 * SZ + ix] + s2p[3 * SZ + ix];
        unsigned u = __float_as_uint(s2v);
        u = (u & 0x80000000u) ? ~u : (u | 0x80000000u);   // order-preserving map
        keys[t] = ((uint64_t)u << 16) | (unsigned)t;      // unique -> no ties
    }
    __syncthreads();

    const int le = tid & 63;
    const int e  = c * 64 + le;
    const int q  = tid >> 6;         // 0..7
    const uint64_t myk = keys[e];
    const uint64_t* kp = keys + q * 256;
    int cnt = 0;
#pragma unroll 8
    for (int kk = 0; kk < 256; ++kk) cnt += (int)(kp[kk] > myk);
    part[tid] = cnt;
    __syncthreads();

    if (tid < 64) {
        int rank = 0;
#pragma unroll
        for (int g = 0; g < 8; ++g) rank += part[tid + 64 * g];
        int ee = c * 64 + tid;
        size_t ix = (size_t)b * N_ + ee;
        float v = s2p[ix] + s2p[SZ + ix] + s2p[2 * SZ + ix] + s2p[3 * SZ + ix];
        ssort[b * N_ + rank] = v;
        sord[b * N_ + rank]  = ee;
        e2p[b * N_ + rank] = expf(v);
        e2n[b * N_ + rank] = expf(ALPHA * v);
    }
}

// ---------------- KX: chunk-local full prefixes, bf16-packed (blocks 0..255) ∪ scalar scan+cutoffs (256..263) ----------------
__global__ __launch_bounds__(512) void kx_scan(const float* __restrict__ Wh,
                                               const int* __restrict__ sord,
                                               const float* __restrict__ e2p,
                                               const float* __restrict__ e2n,
                                               const float* __restrict__ ssort,
                                               const float* __restrict__ s1p,
                                               unsigned* __restrict__ SPN,
                                               float2* __restrict__ DPN,
                                               int* __restrict__ kcut) {
    __shared__ float2 qt[4][FO];     // chunk part
    __shared__ float sv[N_];         // scan part
    __shared__ float2 wsum[8];
    const int tid = threadIdx.x;
    const int bid = blockIdx.x;
    const size_t SZ = (size_t)B_ * N_;

    if (bid < 256) {
        // one 64-chunk; q = tid>>7 owns 16 positions; full chunk-local prefixes out
        const int b = bid >> 5, ch = bid & 31;
        const int f = tid & 127, q = tid >> 7;
        const size_t base = (size_t)b * N_;
        const int ks = ch * CHUNK + q * 16;

        int ords[16]; float wp[16], wn[16], xv[16];
#pragma unroll
        for (int j = 0; j < 16; ++j) ords[j] = sord[base + ks + j];
#pragma unroll
        for (int j = 0; j < 16; ++j) { wp[j] = e2p[base + ks + j]; wn[j] = e2n[base + ks + j]; }
#pragma unroll
        for (int j = 0; j < 16; ++j) xv[j] = Wh[(base + ords[j]) * FO + f];

        float2 s[16];
        float ap = 0.f, an = 0.f;
#pragma unroll
        for (int j = 0; j < 16; ++j) {
            ap += wp[j] * xv[j];
            an += wn[j] * xv[j];
            s[j] = make_float2(ap, an);
        }
        qt[q][f] = make_float2(ap, an);
        __syncthreads();

        float op = 0.f, on = 0.f;
#pragma unroll
        for (int q2 = 0; q2 < 3; ++q2)
            if (q2 < q) { op += qt[q2][f].x; on += qt[q2][f].y; }

#pragma unroll
        for (int j = 0; j < 16; ++j)
            SPN[(base + ks + j) * FO + f] = pack_pn(s[j].x + op, s[j].y + on);
    } else {
        // per-batch scalar scan + cutoffs
        const int b = bid - 256;
        const size_t base = (size_t)b * N_;

        float v[4], pv[4], nv[4], lp[4], ln[4];
        *(float4*)&v[0]  = *(const float4*)&ssort[base + tid * 4];
        *(float4*)&pv[0] = *(const float4*)&e2p[base + tid * 4];
        *(float4*)&nv[0] = *(const float4*)&e2n[base + tid * 4];
        float ap = 0.f, an = 0.f;
#pragma unroll
        for (int j = 0; j < 4; ++j) {
            sv[tid * 4 + j] = v[j];
            ap += pv[j]; lp[j] = ap;
            an += nv[j]; ln[j] = an;
        }

        float ip = ap, in2 = an;
        const int lane = tid & 63;
#pragma unroll
        for (int off = 1; off < 64; off <<= 1) {
            float tpv = __shfl_up(ip, off);
            float tnv = __shfl_up(in2, off);
            if (lane >= off) { ip += tpv; in2 += tnv; }
        }
        if (lane == 63) wsum[tid >> 6] = make_float2(ip, in2);
        __syncthreads();

        float basP = ip - ap, basN = in2 - an;
        const int w = tid >> 6;
#pragma unroll
        for (int w2 = 0; w2 < 7; ++w2)
            if (w2 < w) { basP += wsum[w2].x; basN += wsum[w2].y; }
#pragma unroll
        for (int j = 0; j < 4; ++j)
            DPN[base + tid * 4 + j] = make_float2(lp[j] + basP, ln[j] + basN);

        float tgt[4];
        int lo[4], hi[4];
#pragma unroll
        for (int r = 0; r < 4; ++r) {
            size_t row = base + tid + 512 * r;
            tgt[r] = -(s1p[row] + s1p[SZ + row] + s1p[2 * SZ + row] + s1p[3 * SZ + row]);
            lo[r] = 0; hi[r] = N_;
        }
#pragma unroll
        for (int step = 0; step < 11; ++step) {
#pragma unroll
            for (int r = 0; r < 4; ++r) {
                int mid = (lo[r] + hi[r]) >> 1;
                bool live = lo[r] < hi[r];
                float pv2 = sv[mid & (N_ - 1)];
                bool cc = live && (pv2 >= tgt[r]);
                lo[r] = cc ? mid + 1 : lo[r];
                hi[r] = (live && !cc) ? mid : hi[r];
            }
        }
#pragma unroll
        for (int r = 0; r < 4; ++r) kcut[base + tid + 512 * r] = lo[r];
    }
}

// ---------------- K4: per-32-row block; ct scan + 1 packed prefix load per row ----------------
// grid = 512 blocks, 512 threads (4 rows x 128 f per iteration, 8 iters)
__global__ __launch_bounds__(512) void k4_final(const float* __restrict__ s1p,
                                                const int* __restrict__ kcut,
                                                const float2* __restrict__ DPN,
                                                const unsigned* __restrict__ SPN,
                                                float* __restrict__ out) {
    __shared__ float2 ct[NCHUNK][FO];        // 32 KB -> becomes exclusive prefix
    __shared__ float2 qTot[4][FO];           // 4 KB
    __shared__ float sntN_lds[FO];
    __shared__ float2 s1e_lds[32];           // (exp(s1), exp(a*s1)) per row
    __shared__ float2 dpn_lds[32];           // DPN[km1] per row
    __shared__ int    k_lds[32];

    const int bid = blockIdx.x;
    const int b   = bid >> 6;                // 64 blocks per batch
    const int r0  = (bid & 63) * 32;         // first row of this block
    const int tid = threadIdx.x;
    const int f = tid & 127, rr = tid >> 7;  // rr = 0..3
    const size_t base = (size_t)b * N_;
    const size_t SZ = (size_t)B_ * N_;

    // 1) stage 32 chunk totals (last position of each chunk)
    for (int idx = tid; idx < NCHUNK * FO; idx += 512) {
        int c = idx >> 7, ff = idx & 127;
        ct[c][ff] = unpack_pn(SPN[(base + c * CHUNK + CHUNK - 1) * FO + ff]);
    }
    // stage per-row scalars
    if (tid < 32) {
        int row = r0 + tid;
        int k = kcut[base + row];
        k_lds[tid] = k;
        size_t rix = base + row;
        float s1v = s1p[rix] + s1p[SZ + rix] + s1p[2 * SZ + rix] + s1p[3 * SZ + rix];
        s1e_lds[tid] = make_float2(expf(s1v), expf(ALPHA * s1v));
        dpn_lds[tid] = (k > 0) ? DPN[base + k - 1] : make_float2(0.f, 0.f);
    }
    __syncthreads();

    // 2) exclusive scan over chunks: 4 quarters of 8 + fixup
    float rp = 0.f, rn = 0.f;
    for (int c = rr * 8; c < rr * 8 + 8; ++c) {
        float2 t = ct[c][f];
        ct[c][f] = make_float2(rp, rn);
        rp += t.x; rn += t.y;
    }
    qTot[rr][f] = make_float2(rp, rn);
    __syncthreads();
    float addP = 0.f, addN = 0.f;
#pragma unroll
    for (int q2 = 0; q2 < 3; ++q2)
        if (q2 < rr) { addP += qTot[q2][f].x; addN += qTot[q2][f].y; }
    if (rr > 0) {
        for (int c = rr * 8; c < rr * 8 + 8; ++c) {
            float2 t = ct[c][f];
            ct[c][f] = make_float2(t.x + addP, t.y + addN);
        }
    }
    if (tid < FO)
        sntN_lds[tid] = qTot[0][tid].y + qTot[1][tid].y + qTot[2][tid].y + qTot[3][tid].y;
    __syncthreads();

    const float dnt = DPN[base + N_ - 1].y;
    const float sntN = sntN_lds[f];

    // 3) 8 iterations x 4 rows; one coalesced packed prefix load per row
#pragma unroll 2
    for (int it = 0; it < 8; ++it) {
        const int lr   = it * 4 + rr;        // local row 0..31
        const int row  = r0 + lr;
        const float2 e1 = s1e_lds[lr];
        const float2 d  = dpn_lds[lr];
        const int k = k_lds[lr];

        float sp = 0.f, sn = 0.f;
        if (k > 0) {
            const int km1 = k - 1;
            const int c32 = km1 >> 6;          // CHUNK=64
            float2 o  = ct[c32][f];
            float2 sl = unpack_pn(SPN[(base + km1) * FO + f]);
            sp = o.x + sl.x;
            sn = o.y + sl.y;
        }
        const float den = e1.x * d.x + e1.y * (dnt - d.y);
        const float num = e1.x * sp + e1.y * (sntN - sn);
        const float o = num / den;
        out[((size_t)b * N_ + row) * FO + f] = (o > 0.f) ? o : (expf(o) - 1.f);
    }
}

// ---------------- launch ----------------
extern "C" void kernel_launch(void* const* d_in, const int* in_sizes, int n_in,
                              void* d_out, int out_size, void* d_ws, size_t ws_size,
                              hipStream_t stream) {
    const float* h = (const float*)d_in[0];
    const float* W = (const float*)d_in[1];
    const float* a = (const float*)d_in[2];
    float* out = (float*)d_out;
    float* ws = (float*)d_ws;

    float*    Wh    = ws + OFF_WH;
    float*    s1p   = ws + OFF_S1P;
    float*    s2p   = ws + OFF_S2P;
    float*    ssort = ws + OFF_SSORT;
    int*      sord  = (int*)(ws + OFF_SORD);
    float*    e2p   = ws + OFF_E2P;
    float*    e2n   = ws + OFF_E2N;
    float2*   DPN   = (float2*)(ws + OFF_DPN);
    int*      kcut  = (int*)(ws + OFF_KCUT);
    unsigned* SPN   = (unsigned*)(ws + OFF_SPN);

    k1_gemm<<<dim3(B_ * N_ / 64), dim3(512), 0, stream>>>(h, W, a, Wh, s1p, s2p);
    k2a_rank<<<dim3(B_ * 32), dim3(512), 0, stream>>>(s2p, ssort, sord, e2p, e2n);
    kx_scan<<<dim3(264), dim3(512), 0, stream>>>(Wh, sord, e2p, e2n, ssort, s1p,
                                                 SPN, DPN, kcut);
    k4_final<<<dim3(512), dim3(512), 0, stream>>>(s1p, kcut, DPN, SPN, out);
}